// Round 5
// baseline (138.347 us; speedup 1.0000x reference)
//
#include <hip/hip_runtime.h>
#include <math.h>

// Box-embedding conditional-probability loss.
// R5: force 16-deep MLP with inline-asm loads the compiler cannot sink.
// R3 (sched_barrier) and R4 (waves-per-eu=4) were NULL EDITS - VGPR stayed
// 36, proving the scheduler kept sinking loads to ~4-5 in flight. Here:
// 16x asm volatile global_load_dwordx4 issued back-to-back, then chunk-wise
// s_waitcnt vmcnt(12/8/4/0) asms with "+v" ties so consumers cannot be
// hoisted above the wait. ~64 payload VGPRs pinned live -> real MLP test.
// Primary theory (delivered-gather ceiling ~6.2 TB/s) predicts dur
// UNCHANGED at ~41-43us; falsifier: dur <= 32us revives the latency model.

typedef float f32x4 __attribute__((ext_vector_type(4)));

#define EPSF 1e-8f

__device__ __forceinline__ f32x4 async_load(const f32x4* p) {
    f32x4 r;
    asm volatile("global_load_dwordx4 %0, %1, off" : "=v"(r) : "v"(p));
    return r;
}

__global__ __launch_bounds__(256) void box_loss_kernel(
    const int* __restrict__ t1x, const int* __restrict__ t2x,
    const float* __restrict__ min_t, const float* __restrict__ delta_t,
    float* __restrict__ out, int B)
{
    const float MIN_MEAN   = (float)((0.0001 + 0.01) / 2.0);          // 0.00505
    const float MIN_VAR    = (float)(0.01 - (0.0001 + 0.01) / 2.0);   // 0.00495
    const float DELTA_MEAN = (float)((0.9 + 0.999) / 2.0);            // 0.9495
    const float DELTA_VAR  = (float)(0.999 - (0.9 + 0.999) / 2.0);    // 0.0495

    int gid  = blockIdx.x * blockDim.x + threadIdx.x;
    int s    = gid >> 3;            // one 8-lane group per sample
    int lane = threadIdx.x & 7;
    if (s >= B) return;

    size_t i1 = (size_t)t1x[s];
    size_t i2 = (size_t)t2x[s];

    const f32x4* m1 = reinterpret_cast<const f32x4*>(min_t   + i1 * 128) + lane;
    const f32x4* d1 = reinterpret_cast<const f32x4*>(delta_t + i1 * 128) + lane;
    const f32x4* m2 = reinterpret_cast<const f32x4*>(min_t   + i2 * 128) + lane;
    const f32x4* d2 = reinterpret_cast<const f32x4*>(delta_t + i2 * 128) + lane;

    // Issue ALL 16 loads back-to-back (volatile asm preserves issue order).
    f32x4 A1[4], B1[4], A2[4], B2[4];
    #pragma unroll
    for (int c = 0; c < 4; ++c) {
        A1[c] = async_load(m1 + c * 8);
        B1[c] = async_load(d1 + c * 8);
        A2[c] = async_load(m2 + c * 8);
        B2[c] = async_load(d2 + c * 8);
    }

    float p1 = 1.f, p2 = 1.f, pm = 1.f, pj = 1.f;
    float wmin = 1e30f;   // running min of meet width -> disjoint iff <= 0

    // Consume chunk-by-chunk: vmcnt(12/8/4/0) waits for the oldest 4/8/12/16
    // loads; "+v" ties keep consumers below the wait.
#define WAIT_CHUNK(N, c)                                                     \
    asm volatile("s_waitcnt vmcnt(" #N ")"                                   \
                 : "+v"(A1[c]), "+v"(B1[c]), "+v"(A2[c]), "+v"(B2[c]))

#define DO_CHUNK(c)                                                          \
    _Pragma("unroll")                                                        \
    for (int k = 0; k < 4; ++k) {                                            \
        float t1min = fmaf(A1[c][k], MIN_VAR, MIN_MEAN);                     \
        float w1    = fmaf(B1[c][k], DELTA_VAR, DELTA_MEAN);                 \
        float t2min = fmaf(A2[c][k], MIN_VAR, MIN_MEAN);                     \
        float w2    = fmaf(B2[c][k], DELTA_VAR, DELTA_MEAN);                 \
        float t1max = t1min + w1;                                            \
        float t2max = t2min + w2;                                            \
        float mm_ = fmaxf(t1min, t2min);                                     \
        float mM_ = fminf(t1max, t2max);                                     \
        float jm_ = fminf(t1min, t2min);                                     \
        float jM_ = fmaxf(t1max, t2max);                                     \
        float wm = mM_ - mm_;                                                \
        float wj = jM_ - jm_;                                                \
        wmin = fminf(wmin, wm);                                              \
        p1 *= w1;                                                            \
        p2 *= w2;                                                            \
        pm *= fmaxf(wm, EPSF);                                               \
        pj *= wj;                                                            \
    }

    WAIT_CHUNK(12, 0); DO_CHUNK(0);
    WAIT_CHUNK(8, 1);  DO_CHUNK(1);
    WAIT_CHUNK(4, 2);  DO_CHUNK(2);
    WAIT_CHUNK(0, 3);  DO_CHUNK(3);

#undef WAIT_CHUNK
#undef DO_CHUNK

    // one log per quantity per lane (products of 16 widths: ~[0.2, 2], safe)
    float l1 = __logf(p1);
    float l2 = __logf(p2);
    float lm = __logf(pm);
    float lj = __logf(pj);

    // butterfly across the 8-lane group (masks 4,2,1 stay in-group)
    #pragma unroll
    for (int m = 4; m >= 1; m >>= 1) {
        l1   += __shfl_xor(l1,   m, 64);
        l2   += __shfl_xor(l2,   m, 64);
        lm   += __shfl_xor(lm,   m, 64);
        lj   += __shfl_xor(lj,   m, 64);
        wmin  = fminf(wmin, __shfl_xor(wmin, m, 64));
    }

    if (lane == 0) {
        float cond = lm - l2;
        float pos, neg;
        if (wmin <= 0.f) {                  // disjoint
            pos = lj - l1;                  // -(t1_log - join_log)
            neg = 0.f;
        } else {
            pos = -cond;
            // precise path: cancellation near cond==0
            neg = -logf(fmaxf(1.f - expf(cond), EPSF));
        }
        out[s]     = pos;   // train_pos_prob
        out[B + s] = neg;   // train_neg_prob
    }
}

extern "C" void kernel_launch(void* const* d_in, const int* in_sizes, int n_in,
                              void* d_out, int out_size, void* d_ws, size_t ws_size,
                              hipStream_t stream) {
    const int*   t1x     = (const int*)d_in[0];
    const int*   t2x     = (const int*)d_in[1];
    const float* min_t   = (const float*)d_in[2];
    const float* delta_t = (const float*)d_in[3];
    float*       out     = (float*)d_out;

    int B = in_sizes[0];
    int threads = 256;                       // 32 samples per block
    int blocks  = (B * 8 + threads - 1) / threads;
    box_loss_kernel<<<blocks, threads, 0, stream>>>(t1x, t2x, min_t, delta_t, out, B);
}